// Round 20
// baseline (174.840 us; speedup 1.0000x reference)
//
#include <hip/hip_runtime.h>

#define N_NODES 100000
#define N_EDGES 1600000
#define IN_DIM 128
#define HID_DIM 128
#define OUT_DIM 64

// dst-bucketed binning
#define BKT_SHIFT 8                      // 256 nodes per bucket
#define NPB 256                          // nodes per bucket
#define NBKT ((N_NODES + NPB - 1) / NPB) // 391
#define BKT_CAP 5120                     // mean 4092 -> large headroom
#define BIN_CHUNK 4096                   // edges per bin block

// csr_conv block-role split
#define CC_CSR NBKT                      // 391
#define CC_CONV (N_NODES / 4)            // 25000
#define CC_WT 192                        // 128*256/256 + 128*128/256

// gemm12 geometry
#define G_WAVES 12
#define G_ROWS (G_WAVES * 16)            // 192 rows per block
#define G_BLOCKS ((N_NODES + G_ROWS - 1) / G_ROWS)   // 521

typedef __attribute__((ext_vector_type(8))) short short8;
typedef __attribute__((ext_vector_type(4))) float f32x4;
typedef __attribute__((ext_vector_type(2))) short s16x2;

// ---------------------------------------------------------------------------
// helpers
// ---------------------------------------------------------------------------
__device__ __forceinline__ float bf2f(unsigned short h) {
    unsigned int u = ((unsigned int)h) << 16;
    return __builtin_bit_cast(float, u);
}
__device__ __forceinline__ unsigned short f2bf(float f) {
    unsigned int u = __builtin_bit_cast(unsigned int, f);
    u += 0x7FFFu + ((u >> 16) & 1u);
    return (unsigned short)(u >> 16);
}

#define XSCALE 21.166666f        // 127/6  (x ~ N(0,1); clamp at 6 sigma)
#define XINV   0.047244094f      // 6/127
#define ZQ     10.583333f        // 127/12 (z sigma ~0.73 -> 16-sigma range)
#define ZINV   0.094488189f      // 12/127

// packed int8 pair-accumulate: v = 4 int8 (dims 4d+0..3);
// L += sext(b0),sext(b2); H += sext(b1),sext(b3)
__device__ __forceinline__ void acc_i8x4(unsigned v, s16x2& L, s16x2& H) {
    s16x2 sv = __builtin_bit_cast(s16x2, v);
    H += sv >> 8;
    L += (s16x2)(sv << 8) >> 8;
}

// W tables stored PRE-SWIZZLED: element (m,k) at (m*KW+k) ^ ((m&7)<<3);
// linear LDS stage + swizzled ds_read -> 2-way bank alias only (free, m136).
__device__ __forceinline__ int wswz(int m, int k, int KW) {
    return (m * KW + k) ^ ((m & 7) << 3);
}

// ---------------------------------------------------------------------------
// bin kernel: scatter edges into fixed-capacity dst buckets (LDS-counted).
// ---------------------------------------------------------------------------
__global__ __launch_bounds__(256) void bin_kernel(
        const int* __restrict__ src, const int* __restrict__ dst,
        int* __restrict__ cursor, unsigned* __restrict__ binned) {
    __shared__ int cnt[NBKT];
    __shared__ int sbase[NBKT];
    const int b = blockIdx.x, t = threadIdx.x;
    for (int i = t; i < NBKT; i += 256) cnt[i] = 0;
    __syncthreads();
    const int e0 = b * BIN_CHUNK;
    unsigned val[16];
    int bkt[16], rank[16];
    #pragma unroll
    for (int k = 0; k < 16; ++k) {
        int e = e0 + k * 256 + t;
        if (e < N_EDGES) {
            int d = dst[e];
            bkt[k] = d >> BKT_SHIFT;
            val[k] = (unsigned)src[e] | ((unsigned)(d & (NPB - 1)) << 17);
            rank[k] = atomicAdd(&cnt[bkt[k]], 1);
        } else {
            bkt[k] = -1;
        }
    }
    __syncthreads();
    for (int i = t; i < NBKT; i += 256)
        sbase[i] = cnt[i] ? atomicAdd(&cursor[i], cnt[i]) : 0;
    __syncthreads();
    #pragma unroll
    for (int k = 0; k < 16; ++k)
        if (bkt[k] >= 0)
            binned[(size_t)bkt[k] * BKT_CAP + sbase[bkt[k]] + rank[k]] = val[k];
}

// ---------------------------------------------------------------------------
// csr_conv: blocks [0,391) build CSR from buckets; [391,25391) convert x ->
// xh bf16 (row-major) + xq int8 (column-chunked [2][N][64]); rest
// transpose+swizzle weights.
// ---------------------------------------------------------------------------
__global__ __launch_bounds__(256) void csr_conv_kernel(
        const unsigned* __restrict__ binned, const int* __restrict__ cursor,
        int* __restrict__ offsets, int* __restrict__ csr_src,
        const float* __restrict__ x, unsigned short* __restrict__ xh,
        unsigned char* __restrict__ xq,
        const float* __restrict__ W1l, const float* __restrict__ W1r,
        const float* __restrict__ W2l, const float* __restrict__ W2r,
        unsigned short* __restrict__ WT1, unsigned short* __restrict__ WT2T) {
    int b = blockIdx.x;
    const int t = threadIdx.x;

    if (b < CC_CSR) {
        __shared__ int deg[NPB];
        __shared__ int cur[NPB];
        __shared__ int wsums[4];
        __shared__ int sbase_sh;
        const int lane = t & 63, wid = t >> 6;

        int ps = 0;
        for (int i = t; i < b; i += 256) ps += cursor[i];
        #pragma unroll
        for (int off = 32; off; off >>= 1) ps += __shfl_down(ps, off, 64);
        if (lane == 0) wsums[wid] = ps;
        deg[t] = 0;
        __syncthreads();
        if (t == 0) sbase_sh = wsums[0] + wsums[1] + wsums[2] + wsums[3];
        __syncthreads();
        const int base = sbase_sh;
        const int n0 = b << BKT_SHIFT;
        const int cnt = cursor[b];
        const unsigned* __restrict__ ebase = binned + (size_t)b * BKT_CAP;

        for (int i = t; i < cnt; i += 256)
            atomicAdd(&deg[ebase[i] >> 17], 1);
        __syncthreads();

        int d = deg[t];
        int s = d;
        #pragma unroll
        for (int off = 1; off < 64; off <<= 1) {
            int u = __shfl_up(s, off, 64);
            if (lane >= off) s += u;
        }
        if (lane == 63) wsums[wid] = s;
        __syncthreads();
        int add = 0;
        for (int w = 0; w < wid; ++w) add += wsums[w];
        const int excl = s + add - d;
        cur[t] = excl;
        const int n = n0 + t;
        if (n <= N_NODES) offsets[n] = base + excl;
        __syncthreads();

        for (int i = t; i < cnt; i += 256) {
            unsigned v = ebase[i];
            int pos = atomicAdd(&cur[v >> 17], 1);
            csr_src[base + pos] = (int)(v & 0x1FFFFu);
        }
        return;
    }

    b -= CC_CSR;
    if (b < CC_CONV) {
        const int w = t >> 6, lane = t & 63;
        const int row = b * 4 + w;
        float2 v = *(const float2*)(x + (size_t)row * 128 + lane * 2);
        unsigned pk = (unsigned)f2bf(v.x) | ((unsigned)f2bf(v.y) << 16);
        *(unsigned*)(xh + (size_t)row * 128 + lane * 2) = pk;
        int q0 = (int)__float2int_rn(fminf(fmaxf(v.x * XSCALE, -127.f), 127.f));
        int q1 = (int)__float2int_rn(fminf(fmaxf(v.y * XSCALE, -127.f), 127.f));
        const int ch = lane >> 5;          // dim chunk 0/1
        const int off = (lane & 31) * 2;   // offset within 64-dim chunk
        *(unsigned short*)(xq + ((size_t)ch * N_NODES + row) * 64 + off) =
            (unsigned short)((q0 & 0xFF) | ((q1 & 0xFF) << 8));
        return;
    }

    int i = (b - CC_CONV) * 256 + t;
    if (i < 128 * 256) {
        int m = i >> 8, k = i & 255;
        float v = (k < 128) ? W1l[(size_t)k * 128 + m] : W1r[(size_t)(k - 128) * 128 + m];
        WT1[wswz(m, k, 256)] = f2bf(v);
        return;
    }
    i -= 128 * 256;
    if (i < 128 * 128) {
        int j = i >> 7, k = i & 127;
        float v = (j < 64) ? W2l[(size_t)k * 64 + j] : W2r[(size_t)k * 64 + (j - 64)];
        WT2T[wswz(j, k, 128)] = f2bf(v);
    }
}

// ---------------------------------------------------------------------------
// Layer-1 mean aggregation, XCD-chunked x2 (best-measured variant):
// xq is [2][N][64] i8; chunk = blockIdx&1. Lane = slot(16) x dp(4);
// serial per-lane packed-i16 accum, plain cached loads/stores.
// ---------------------------------------------------------------------------
__global__ __launch_bounds__(256) void agg1_int8(
        const unsigned char* __restrict__ xq, const int* __restrict__ offsets,
        const int* __restrict__ csr_src, unsigned short* __restrict__ mh) {
    const int chunk = blockIdx.x & 1;
    const int bb = blockIdx.x >> 1;
    const int wv = threadIdx.x >> 6;
    const int lane = threadIdx.x & 63;
    const int slot = lane >> 2, dp = lane & 3;
    const int node = (bb * 4 + wv) * 16 + slot;     // up to 100031
    const bool valid = node < N_NODES;
    const int nd = valid ? node : N_NODES - 1;
    const int beg = offsets[nd];
    const int deg = offsets[nd + 1] - beg;
    const unsigned char* __restrict__ xc = xq + (size_t)chunk * N_NODES * 64;

    s16x2 aL[4], aH[4];
    #pragma unroll
    for (int i = 0; i < 4; ++i) { aL[i] = (s16x2)0; aH[i] = (s16x2)0; }

    for (int c = 0; c < deg; c += 4) {
        int my = beg + c + dp;
        int idx4 = csr_src[my < beg + deg ? my : beg];
        #pragma unroll
        for (int jj = 0; jj < 4; ++jj) {
            if (c + jj < deg) {
                int s = __shfl(idx4, slot * 4 + jj, 64);
                uint4 v = *(const uint4*)(xc + (size_t)s * 64 + dp * 16);
                acc_i8x4(v.x, aL[0], aH[0]);
                acc_i8x4(v.y, aL[1], aH[1]);
                acc_i8x4(v.z, aL[2], aH[2]);
                acc_i8x4(v.w, aL[3], aH[3]);
            }
        }
    }

    if (valid) {
        const float inv = (deg > 0) ? XINV / (float)deg : 0.0f;
        unsigned w[8];
        #pragma unroll
        for (int d = 0; d < 4; ++d) {
            w[2 * d]     = (unsigned)f2bf((float)aL[d].x * inv)
                         | ((unsigned)f2bf((float)aH[d].x * inv) << 16);
            w[2 * d + 1] = (unsigned)f2bf((float)aL[d].y * inv)
                         | ((unsigned)f2bf((float)aH[d].y * inv) << 16);
        }
        uint4* o = (uint4*)(mh + (size_t)node * 128 + chunk * 64 + dp * 16);
        o[0] = make_uint4(w[0], w[1], w[2], w[3]);
        o[1] = make_uint4(w[4], w[5], w[6], w[7]);
    }
}

// ---------------------------------------------------------------------------
// FUSED layer GEMMs, 768 threads = 12 waves x 16 rows = 192 rows/block.
// LDS: 64K (Ws1) + 32K (Ws2) + 51K (hT[192][136]) = 147 KB -> 1 block/CU,
// 3 waves/SIMD (R19 was 2). h = relu(mh@W1l + xh@W1r + b1) -> LDS tile ->
// [z|p] = h@[W2l|W2r] (+b2 on p). Waves read back only their own 16 rows.
// ---------------------------------------------------------------------------
__global__ __launch_bounds__(768) void gemm12_kernel(
        const unsigned short* __restrict__ mh, const unsigned short* __restrict__ xh,
        const unsigned short* __restrict__ WT1, const unsigned short* __restrict__ WT2T,
        const float* __restrict__ b1, const float* __restrict__ b2,
        unsigned char* __restrict__ zq, unsigned short* __restrict__ pout) {
    __shared__ unsigned short Ws1[128 * 256];    // 64 KB, swizzled W1
    __shared__ unsigned short Ws2[128 * 128];    // 32 KB, swizzled W2
    __shared__ unsigned short hT[G_ROWS][136];   // 51 KB, h tile (pad 136)
    const int t = threadIdx.x;
    {
        const uint4* s1 = (const uint4*)WT1;
        uint4* d1 = (uint4*)Ws1;
        for (int i = t; i < 4096; i += 768) d1[i] = s1[i];
        const uint4* s2 = (const uint4*)WT2T;
        uint4* d2 = (uint4*)Ws2;
        for (int i = t; i < 2048; i += 768) d2[i] = s2[i];
    }
    const int wave = t >> 6;                      // 0..11
    const int lane = t & 63;
    const int rowbase = blockIdx.x * G_ROWS + wave * 16;
    const int lrow = lane & 15;
    const int kq = (lane >> 4) * 8;
    const int rsw = (lrow & 7) << 3;
    const int colq = lane & 15;
    const int rowq = (lane >> 4) * 4;

    f32x4 acc[8];
    #pragma unroll
    for (int ct = 0; ct < 8; ++ct) acc[ct] = (f32x4)0.f;

    int r0 = rowbase + lrow; if (r0 > N_NODES - 1) r0 = N_NODES - 1;

    __syncthreads();

    // ---- phase 1: h = mh@W1l + xh@W1r ----
    #pragma unroll
    for (int half = 0; half < 2; ++half) {
        const unsigned short* __restrict__ A = half ? xh : mh;
        #pragma unroll
        for (int kc = 0; kc < 4; ++kc) {
            const int kofs = kc * 32 + kq;
            short8 a0 = *(const short8*)(A + (size_t)r0 * 128 + kofs);
            #pragma unroll
            for (int ct = 0; ct < 8; ++ct) {
                short8 bb = *(const short8*)&Ws1[(((ct * 16 + lrow) << 8)
                                                  + (half << 7) + kofs) ^ rsw];
                acc[ct] = __builtin_amdgcn_mfma_f32_16x16x32_bf16(a0, bb, acc[ct], 0, 0, 0);
            }
        }
    }

    // epilogue 1: h-tile (relu + bias) -> LDS, own wave's 16 rows only
    #pragma unroll
    for (int ct = 0; ct < 8; ++ct) {
        const int col = ct * 16 + colq;
        const float bc = b1[col];
        #pragma unroll
        for (int i = 0; i < 4; ++i) {
            const int rl = wave * 16 + rowq + i;
            hT[rl][col] = f2bf(fmaxf(acc[ct][i] + bc, 0.f));
        }
    }
    // no barrier: each wave reads back exactly the rows it wrote

    // ---- phase 2: [z|p] = h@W2 ----
    #pragma unroll
    for (int ct = 0; ct < 8; ++ct) acc[ct] = (f32x4)0.f;

    #pragma unroll
    for (int kc = 0; kc < 4; ++kc) {
        const int kofs = kc * 32 + kq;
        short8 a0 = *(const short8*)&hT[wave * 16 + lrow][kofs];
        #pragma unroll
        for (int ct = 0; ct < 8; ++ct) {
            short8 bb = *(const short8*)&Ws2[(((ct * 16 + lrow) << 7) + kofs) ^ rsw];
            acc[ct] = __builtin_amdgcn_mfma_f32_16x16x32_bf16(a0, bb, acc[ct], 0, 0, 0);
        }
    }

    // epilogue 2: z int8 row-major (fixed scale), p bf16 + b2
    #pragma unroll
    for (int i = 0; i < 4; ++i) {
        const int row = rowbase + rowq + i;
        if (row < N_NODES) {
            unsigned char* zr = zq + (size_t)row * 64 + colq;
            #pragma unroll
            for (int ct = 0; ct < 4; ++ct) {
                float v = fminf(fmaxf(acc[ct][i] * ZQ, -127.f), 127.f);
                zr[ct * 16] = (unsigned char)(signed char)__float2int_rn(v);
            }
        }
    }
    #pragma unroll
    for (int ct = 4; ct < 8; ++ct) {
        const int col = ct * 16 + colq;
        const float bc = b2[col - 64];
        #pragma unroll
        for (int i = 0; i < 4; ++i) {
            const int row = rowbase + rowq + i;
            if (row < N_NODES)
                pout[(size_t)row * 64 + (col - 64)] = f2bf(acc[ct][i] + bc);
        }
    }
}

// ---------------------------------------------------------------------------
// Layer-2 aggregation + final add (best-measured variant):
// out = mean(z)*ZINV + p, serial-per-lane: lane = slot(8) x dp(8).
// uint2 (8 B) loads from row-major zq.
// ---------------------------------------------------------------------------
__global__ __launch_bounds__(256) void agg2_out_kernel(
        const unsigned char* __restrict__ zq, const unsigned short* __restrict__ pout,
        const int* __restrict__ offsets, const int* __restrict__ csr_src,
        float* __restrict__ out) {
    const int wv = threadIdx.x >> 6;
    const int lane = threadIdx.x & 63;
    const int slot = lane >> 3, dp = lane & 7;
    const int node = (blockIdx.x * 4 + wv) * 8 + slot;
    const int beg = offsets[node];
    const int deg = offsets[node + 1] - beg;

    s16x2 aL[2], aH[2];
    #pragma unroll
    for (int i = 0; i < 2; ++i) { aL[i] = (s16x2)0; aH[i] = (s16x2)0; }

    for (int c = 0; c < deg; c += 8) {
        int my = beg + c + dp;
        int idx8 = csr_src[my < beg + deg ? my : beg];
        #pragma unroll
        for (int jj = 0; jj < 8; ++jj) {
            if (c + jj < deg) {
                int s = __shfl(idx8, slot * 8 + jj, 64);
                uint2 v = *(const uint2*)(zq + (size_t)s * 64 + dp * 8);
                acc_i8x4(v.x, aL[0], aH[0]);
                acc_i8x4(v.y, aL[1], aH[1]);
            }
        }
    }

    const float inv = (deg > 0) ? ZINV / (float)deg : 0.0f;
    const unsigned short* pp = pout + (size_t)node * 64 + dp * 8;
    float* oo = out + (size_t)node * 64 + dp * 8;
    #pragma unroll
    for (int d = 0; d < 2; ++d) {
        ushort4 p = *(const ushort4*)(pp + d * 4);
        float4 o;
        o.x = (float)aL[d].x * inv + bf2f(p.x);
        o.y = (float)aH[d].x * inv + bf2f(p.y);
        o.z = (float)aL[d].y * inv + bf2f(p.z);
        o.w = (float)aH[d].y * inv + bf2f(p.w);
        *(float4*)(oo + d * 4) = o;
    }
}

// ---------------------------------------------------------------------------

extern "C" void kernel_launch(void* const* d_in, const int* in_sizes, int n_in,
                              void* d_out, int out_size, void* d_ws, size_t ws_size,
                              hipStream_t stream) {
    const float* x   = (const float*)d_in[0];
    const int*   ei  = (const int*)d_in[1];        // [2, E] int32
    const float* W1l = (const float*)d_in[2];
    const float* W1r = (const float*)d_in[3];
    const float* b1  = (const float*)d_in[4];
    const float* W2l = (const float*)d_in[5];
    const float* W2r = (const float*)d_in[6];
    const float* b2  = (const float*)d_in[7];
    float* out = (float*)d_out;

    const int* src = ei;
    const int* dst = ei + N_EDGES;

    // workspace layout (16B-aligned regions)
    char* ws = (char*)d_ws;
    int* cursor   = (int*)ws;                                  // 512
    int* offsets  = cursor + 512;                              // N+16
    int* csr_src  = offsets + N_NODES + 16;                    // E+64
    unsigned char*  xq  = (unsigned char*)(csr_src + N_EDGES + 64);   // [2][N][64] i8
    unsigned short* xh  = (unsigned short*)(xq + (size_t)N_NODES * 128); // [N][128] bf16
    unsigned short* mh  = xh + (size_t)N_NODES * 128;                 // [N][128] bf16
    unsigned char*  zq  = (unsigned char*)(mh + (size_t)N_NODES * 128); // [N][64] i8
    unsigned short* pout = (unsigned short*)(zq + (size_t)N_NODES * 64); // [N][64] bf16
    unsigned short* WT1  = pout + (size_t)N_NODES * 64;               // 128*256 (swizzled)
    unsigned short* WT2T = WT1 + 128 * 256;                           // 128*128 (swizzled)
    unsigned* binned = (unsigned*)mh;   // alias mh: dead until agg1 writes it

    hipMemsetAsync(cursor, 0, NBKT * sizeof(int), stream);

    bin_kernel<<<(N_EDGES + BIN_CHUNK - 1) / BIN_CHUNK, 256, 0, stream>>>(
        src, dst, cursor, binned);

    // csr (391 blocks) overlapped with x-convert (25000) + W transpose (192)
    csr_conv_kernel<<<CC_CSR + CC_CONV + CC_WT, 256, 0, stream>>>(
        binned, cursor, offsets, csr_src, x, xh, xq,
        W1l, W1r, W2l, W2r, WT1, WT2T);

    // layer 1 aggregation, XCD-chunked x2
    const int a1b = ((N_NODES + 63) / 64) * 2;      // 3126
    agg1_int8<<<a1b, 256, 0, stream>>>(xq, offsets, csr_src, mh);

    // fused layer-1 + layer-2 GEMMs: 768 threads, 12 waves x 16 rows
    gemm12_kernel<<<G_BLOCKS, 768, 0, stream>>>(
        mh, xh, WT1, WT2T, b1, b2, zq, pout);

    // layer-2 aggregation + final add
    agg2_out_kernel<<<N_NODES / 32, 256, 0, stream>>>(zq, pout, offsets, csr_src, out);
}

// Round 21
// 170.311 us; speedup vs baseline: 1.0266x; 1.0266x over previous
//
#include <hip/hip_runtime.h>

#define N_NODES 100000
#define N_EDGES 1600000
#define IN_DIM 128
#define HID_DIM 128
#define OUT_DIM 64

// dst-bucketed binning
#define BKT_SHIFT 8                      // 256 nodes per bucket
#define NPB 256                          // nodes per bucket
#define NBKT ((N_NODES + NPB - 1) / NPB) // 391
#define BKT_CAP 5120                     // mean 4092 -> large headroom
#define BIN_CHUNK 4096                   // edges per bin block

// csr_conv block-role split
#define CC_CSR NBKT                      // 391
#define CC_CONV (N_NODES / 4)            // 25000
#define CC_WT 192                        // 128*256/256 + 128*128/256

typedef __attribute__((ext_vector_type(8))) short short8;
typedef __attribute__((ext_vector_type(4))) float f32x4;
typedef __attribute__((ext_vector_type(2))) short s16x2;

// ---------------------------------------------------------------------------
// helpers
// ---------------------------------------------------------------------------
__device__ __forceinline__ float bf2f(unsigned short h) {
    unsigned int u = ((unsigned int)h) << 16;
    return __builtin_bit_cast(float, u);
}
__device__ __forceinline__ unsigned short f2bf(float f) {
    unsigned int u = __builtin_bit_cast(unsigned int, f);
    u += 0x7FFFu + ((u >> 16) & 1u);
    return (unsigned short)(u >> 16);
}

#define XSCALE 21.166666f        // 127/6  (x ~ N(0,1); clamp at 6 sigma)
#define XINV   0.047244094f      // 6/127
#define ZQ     10.583333f        // 127/12 (z sigma ~0.73 -> 16-sigma range)
#define ZINV   0.094488189f      // 12/127

// packed int8 pair-accumulate: v = 4 int8 (dims 4d+0..3);
// L += sext(b0),sext(b2); H += sext(b1),sext(b3)
__device__ __forceinline__ void acc_i8x4(unsigned v, s16x2& L, s16x2& H) {
    s16x2 sv = __builtin_bit_cast(s16x2, v);
    H += sv >> 8;
    L += (s16x2)(sv << 8) >> 8;
}

// W tables stored PRE-SWIZZLED: element (m,k) at (m*KW+k) ^ ((m&7)<<3);
// linear LDS stage + swizzled ds_read -> 2-way bank alias only (free, m136).
__device__ __forceinline__ int wswz(int m, int k, int KW) {
    return (m * KW + k) ^ ((m & 7) << 3);
}

// ---------------------------------------------------------------------------
// bin kernel: scatter edges into fixed-capacity dst buckets (LDS-counted).
// ---------------------------------------------------------------------------
__global__ __launch_bounds__(256) void bin_kernel(
        const int* __restrict__ src, const int* __restrict__ dst,
        int* __restrict__ cursor, unsigned* __restrict__ binned) {
    __shared__ int cnt[NBKT];
    __shared__ int sbase[NBKT];
    const int b = blockIdx.x, t = threadIdx.x;
    for (int i = t; i < NBKT; i += 256) cnt[i] = 0;
    __syncthreads();
    const int e0 = b * BIN_CHUNK;
    unsigned val[16];
    int bkt[16], rank[16];
    #pragma unroll
    for (int k = 0; k < 16; ++k) {
        int e = e0 + k * 256 + t;
        if (e < N_EDGES) {
            int d = dst[e];
            bkt[k] = d >> BKT_SHIFT;
            val[k] = (unsigned)src[e] | ((unsigned)(d & (NPB - 1)) << 17);
            rank[k] = atomicAdd(&cnt[bkt[k]], 1);
        } else {
            bkt[k] = -1;
        }
    }
    __syncthreads();
    for (int i = t; i < NBKT; i += 256)
        sbase[i] = cnt[i] ? atomicAdd(&cursor[i], cnt[i]) : 0;
    __syncthreads();
    #pragma unroll
    for (int k = 0; k < 16; ++k)
        if (bkt[k] >= 0)
            binned[(size_t)bkt[k] * BKT_CAP + sbase[bkt[k]] + rank[k]] = val[k];
}

// ---------------------------------------------------------------------------
// csr_conv: blocks [0,391) build CSR from buckets; [391,25391) convert x ->
// xh bf16 (row-major) + xq int8 (column-chunked [2][N][64]); rest
// transpose+swizzle weights.
// ---------------------------------------------------------------------------
__global__ __launch_bounds__(256) void csr_conv_kernel(
        const unsigned* __restrict__ binned, const int* __restrict__ cursor,
        int* __restrict__ offsets, int* __restrict__ csr_src,
        const float* __restrict__ x, unsigned short* __restrict__ xh,
        unsigned char* __restrict__ xq,
        const float* __restrict__ W1l, const float* __restrict__ W1r,
        const float* __restrict__ W2l, const float* __restrict__ W2r,
        unsigned short* __restrict__ WT1, unsigned short* __restrict__ WT2T) {
    int b = blockIdx.x;
    const int t = threadIdx.x;

    if (b < CC_CSR) {
        __shared__ int deg[NPB];
        __shared__ int cur[NPB];
        __shared__ int wsums[4];
        __shared__ int sbase_sh;
        const int lane = t & 63, wid = t >> 6;

        int ps = 0;
        for (int i = t; i < b; i += 256) ps += cursor[i];
        #pragma unroll
        for (int off = 32; off; off >>= 1) ps += __shfl_down(ps, off, 64);
        if (lane == 0) wsums[wid] = ps;
        deg[t] = 0;
        __syncthreads();
        if (t == 0) sbase_sh = wsums[0] + wsums[1] + wsums[2] + wsums[3];
        __syncthreads();
        const int base = sbase_sh;
        const int n0 = b << BKT_SHIFT;
        const int cnt = cursor[b];
        const unsigned* __restrict__ ebase = binned + (size_t)b * BKT_CAP;

        for (int i = t; i < cnt; i += 256)
            atomicAdd(&deg[ebase[i] >> 17], 1);
        __syncthreads();

        int d = deg[t];
        int s = d;
        #pragma unroll
        for (int off = 1; off < 64; off <<= 1) {
            int u = __shfl_up(s, off, 64);
            if (lane >= off) s += u;
        }
        if (lane == 63) wsums[wid] = s;
        __syncthreads();
        int add = 0;
        for (int w = 0; w < wid; ++w) add += wsums[w];
        const int excl = s + add - d;
        cur[t] = excl;
        const int n = n0 + t;
        if (n <= N_NODES) offsets[n] = base + excl;
        __syncthreads();

        for (int i = t; i < cnt; i += 256) {
            unsigned v = ebase[i];
            int pos = atomicAdd(&cur[v >> 17], 1);
            csr_src[base + pos] = (int)(v & 0x1FFFFu);
        }
        return;
    }

    b -= CC_CSR;
    if (b < CC_CONV) {
        const int w = t >> 6, lane = t & 63;
        const int row = b * 4 + w;
        float2 v = *(const float2*)(x + (size_t)row * 128 + lane * 2);
        unsigned pk = (unsigned)f2bf(v.x) | ((unsigned)f2bf(v.y) << 16);
        *(unsigned*)(xh + (size_t)row * 128 + lane * 2) = pk;
        int q0 = (int)__float2int_rn(fminf(fmaxf(v.x * XSCALE, -127.f), 127.f));
        int q1 = (int)__float2int_rn(fminf(fmaxf(v.y * XSCALE, -127.f), 127.f));
        const int ch = lane >> 5;          // dim chunk 0/1
        const int off = (lane & 31) * 2;   // offset within 64-dim chunk
        *(unsigned short*)(xq + ((size_t)ch * N_NODES + row) * 64 + off) =
            (unsigned short)((q0 & 0xFF) | ((q1 & 0xFF) << 8));
        return;
    }

    int i = (b - CC_CONV) * 256 + t;
    if (i < 128 * 256) {
        int m = i >> 8, k = i & 255;
        float v = (k < 128) ? W1l[(size_t)k * 128 + m] : W1r[(size_t)(k - 128) * 128 + m];
        WT1[wswz(m, k, 256)] = f2bf(v);
        return;
    }
    i -= 128 * 256;
    if (i < 128 * 128) {
        int j = i >> 7, k = i & 127;
        float v = (j < 64) ? W2l[(size_t)k * 64 + j] : W2r[(size_t)k * 64 + (j - 64)];
        WT2T[wswz(j, k, 128)] = f2bf(v);
    }
}

// ---------------------------------------------------------------------------
// Layer-1 mean aggregation, XCD-chunked x2 (best-measured variant):
// xq is [2][N][64] i8; chunk = blockIdx&1. Lane = slot(16) x dp(4);
// serial per-lane packed-i16 accum, plain cached loads/stores.
// ---------------------------------------------------------------------------
__global__ __launch_bounds__(256) void agg1_int8(
        const unsigned char* __restrict__ xq, const int* __restrict__ offsets,
        const int* __restrict__ csr_src, unsigned short* __restrict__ mh) {
    const int chunk = blockIdx.x & 1;
    const int bb = blockIdx.x >> 1;
    const int wv = threadIdx.x >> 6;
    const int lane = threadIdx.x & 63;
    const int slot = lane >> 2, dp = lane & 3;
    const int node = (bb * 4 + wv) * 16 + slot;     // up to 100031
    const bool valid = node < N_NODES;
    const int nd = valid ? node : N_NODES - 1;
    const int beg = offsets[nd];
    const int deg = offsets[nd + 1] - beg;
    const unsigned char* __restrict__ xc = xq + (size_t)chunk * N_NODES * 64;

    s16x2 aL[4], aH[4];
    #pragma unroll
    for (int i = 0; i < 4; ++i) { aL[i] = (s16x2)0; aH[i] = (s16x2)0; }

    for (int c = 0; c < deg; c += 4) {
        int my = beg + c + dp;
        int idx4 = csr_src[my < beg + deg ? my : beg];
        #pragma unroll
        for (int jj = 0; jj < 4; ++jj) {
            if (c + jj < deg) {
                int s = __shfl(idx4, slot * 4 + jj, 64);
                uint4 v = *(const uint4*)(xc + (size_t)s * 64 + dp * 16);
                acc_i8x4(v.x, aL[0], aH[0]);
                acc_i8x4(v.y, aL[1], aH[1]);
                acc_i8x4(v.z, aL[2], aH[2]);
                acc_i8x4(v.w, aL[3], aH[3]);
            }
        }
    }

    if (valid) {
        const float inv = (deg > 0) ? XINV / (float)deg : 0.0f;
        unsigned w[8];
        #pragma unroll
        for (int d = 0; d < 4; ++d) {
            w[2 * d]     = (unsigned)f2bf((float)aL[d].x * inv)
                         | ((unsigned)f2bf((float)aH[d].x * inv) << 16);
            w[2 * d + 1] = (unsigned)f2bf((float)aL[d].y * inv)
                         | ((unsigned)f2bf((float)aH[d].y * inv) << 16);
        }
        uint4* o = (uint4*)(mh + (size_t)node * 128 + chunk * 64 + dp * 16);
        o[0] = make_uint4(w[0], w[1], w[2], w[3]);
        o[1] = make_uint4(w[4], w[5], w[6], w[7]);
    }
}

// ---------------------------------------------------------------------------
// FUSED layer GEMMs, 512 threads = 8 waves x 16 rows (best-measured):
// LDS 130 KB -> 1 block/CU, 2 waves/SIMD. h = relu(mh@W1l + xh@W1r + b1)
// -> LDS tile -> [z|p] = h@[W2l|W2r] (+b2 on p). Waves read back only
// their own 16 rows (no 2nd barrier).
// ---------------------------------------------------------------------------
__global__ __launch_bounds__(512) void gemm12_kernel(
        const unsigned short* __restrict__ mh, const unsigned short* __restrict__ xh,
        const unsigned short* __restrict__ WT1, const unsigned short* __restrict__ WT2T,
        const float* __restrict__ b1, const float* __restrict__ b2,
        unsigned char* __restrict__ zq, unsigned short* __restrict__ pout) {
    __shared__ unsigned short Ws1[128 * 256];    // 64 KB, swizzled W1
    __shared__ unsigned short Ws2[128 * 128];    // 32 KB, swizzled W2
    __shared__ unsigned short hT[128][136];      // 34 KB, h tile (pad 136)
    const int t = threadIdx.x;
    {
        const uint4* s1 = (const uint4*)WT1;
        uint4* d1 = (uint4*)Ws1;
        #pragma unroll
        for (int r = 0; r < 8; ++r) d1[t + r * 512] = s1[t + r * 512];
        const uint4* s2 = (const uint4*)WT2T;
        uint4* d2 = (uint4*)Ws2;
        #pragma unroll
        for (int r = 0; r < 4; ++r) d2[t + r * 512] = s2[t + r * 512];
    }
    const int wave = t >> 6;                      // 0..7
    const int lane = t & 63;
    const int rowbase = blockIdx.x * 128 + wave * 16;
    const int lrow = lane & 15;
    const int kq = (lane >> 4) * 8;
    const int rsw = (lrow & 7) << 3;
    const int colq = lane & 15;
    const int rowq = (lane >> 4) * 4;

    f32x4 acc[8];
    #pragma unroll
    for (int ct = 0; ct < 8; ++ct) acc[ct] = (f32x4)0.f;

    int r0 = rowbase + lrow; if (r0 > N_NODES - 1) r0 = N_NODES - 1;

    __syncthreads();

    // ---- phase 1: h = mh@W1l + xh@W1r ----
    #pragma unroll
    for (int half = 0; half < 2; ++half) {
        const unsigned short* __restrict__ A = half ? xh : mh;
        #pragma unroll
        for (int kc = 0; kc < 4; ++kc) {
            const int kofs = kc * 32 + kq;
            short8 a0 = *(const short8*)(A + (size_t)r0 * 128 + kofs);
            #pragma unroll
            for (int ct = 0; ct < 8; ++ct) {
                short8 bb = *(const short8*)&Ws1[(((ct * 16 + lrow) << 8)
                                                  + (half << 7) + kofs) ^ rsw];
                acc[ct] = __builtin_amdgcn_mfma_f32_16x16x32_bf16(a0, bb, acc[ct], 0, 0, 0);
            }
        }
    }

    // epilogue 1: h-tile (relu + bias) -> LDS, own wave's 16 rows only
    #pragma unroll
    for (int ct = 0; ct < 8; ++ct) {
        const int col = ct * 16 + colq;
        const float bc = b1[col];
        #pragma unroll
        for (int i = 0; i < 4; ++i) {
            const int rl = wave * 16 + rowq + i;
            hT[rl][col] = f2bf(fmaxf(acc[ct][i] + bc, 0.f));
        }
    }
    // no barrier: each wave reads back exactly the rows it wrote

    // ---- phase 2: [z|p] = h@W2 ----
    #pragma unroll
    for (int ct = 0; ct < 8; ++ct) acc[ct] = (f32x4)0.f;

    #pragma unroll
    for (int kc = 0; kc < 4; ++kc) {
        const int kofs = kc * 32 + kq;
        short8 a0 = *(const short8*)&hT[wave * 16 + lrow][kofs];
        #pragma unroll
        for (int ct = 0; ct < 8; ++ct) {
            short8 bb = *(const short8*)&Ws2[(((ct * 16 + lrow) << 7) + kofs) ^ rsw];
            acc[ct] = __builtin_amdgcn_mfma_f32_16x16x32_bf16(a0, bb, acc[ct], 0, 0, 0);
        }
    }

    // epilogue 2: z int8 row-major (fixed scale), p bf16 + b2
    #pragma unroll
    for (int i = 0; i < 4; ++i) {
        const int row = rowbase + rowq + i;
        if (row < N_NODES) {
            unsigned char* zr = zq + (size_t)row * 64 + colq;
            #pragma unroll
            for (int ct = 0; ct < 4; ++ct) {
                float v = fminf(fmaxf(acc[ct][i] * ZQ, -127.f), 127.f);
                zr[ct * 16] = (unsigned char)(signed char)__float2int_rn(v);
            }
        }
    }
    #pragma unroll
    for (int ct = 4; ct < 8; ++ct) {
        const int col = ct * 16 + colq;
        const float bc = b2[col - 64];
        #pragma unroll
        for (int i = 0; i < 4; ++i) {
            const int row = rowbase + rowq + i;
            if (row < N_NODES)
                pout[(size_t)row * 64 + (col - 64)] = f2bf(acc[ct][i] + bc);
        }
    }
}

// ---------------------------------------------------------------------------
// Layer-2 aggregation + final add (best-measured variant):
// out = mean(z)*ZINV + p, serial-per-lane: lane = slot(8) x dp(8).
// uint2 (8 B) loads from row-major zq.
// ---------------------------------------------------------------------------
__global__ __launch_bounds__(256) void agg2_out_kernel(
        const unsigned char* __restrict__ zq, const unsigned short* __restrict__ pout,
        const int* __restrict__ offsets, const int* __restrict__ csr_src,
        float* __restrict__ out) {
    const int wv = threadIdx.x >> 6;
    const int lane = threadIdx.x & 63;
    const int slot = lane >> 3, dp = lane & 7;
    const int node = (blockIdx.x * 4 + wv) * 8 + slot;
    const int beg = offsets[node];
    const int deg = offsets[node + 1] - beg;

    s16x2 aL[2], aH[2];
    #pragma unroll
    for (int i = 0; i < 2; ++i) { aL[i] = (s16x2)0; aH[i] = (s16x2)0; }

    for (int c = 0; c < deg; c += 8) {
        int my = beg + c + dp;
        int idx8 = csr_src[my < beg + deg ? my : beg];
        #pragma unroll
        for (int jj = 0; jj < 8; ++jj) {
            if (c + jj < deg) {
                int s = __shfl(idx8, slot * 8 + jj, 64);
                uint2 v = *(const uint2*)(zq + (size_t)s * 64 + dp * 8);
                acc_i8x4(v.x, aL[0], aH[0]);
                acc_i8x4(v.y, aL[1], aH[1]);
            }
        }
    }

    const float inv = (deg > 0) ? ZINV / (float)deg : 0.0f;
    const unsigned short* pp = pout + (size_t)node * 64 + dp * 8;
    float* oo = out + (size_t)node * 64 + dp * 8;
    #pragma unroll
    for (int d = 0; d < 2; ++d) {
        ushort4 p = *(const ushort4*)(pp + d * 4);
        float4 o;
        o.x = (float)aL[d].x * inv + bf2f(p.x);
        o.y = (float)aH[d].x * inv + bf2f(p.y);
        o.z = (float)aL[d].y * inv + bf2f(p.z);
        o.w = (float)aH[d].y * inv + bf2f(p.w);
        *(float4*)(oo + d * 4) = o;
    }
}

// ---------------------------------------------------------------------------

extern "C" void kernel_launch(void* const* d_in, const int* in_sizes, int n_in,
                              void* d_out, int out_size, void* d_ws, size_t ws_size,
                              hipStream_t stream) {
    const float* x   = (const float*)d_in[0];
    const int*   ei  = (const int*)d_in[1];        // [2, E] int32
    const float* W1l = (const float*)d_in[2];
    const float* W1r = (const float*)d_in[3];
    const float* b1  = (const float*)d_in[4];
    const float* W2l = (const float*)d_in[5];
    const float* W2r = (const float*)d_in[6];
    const float* b2  = (const float*)d_in[7];
    float* out = (float*)d_out;

    const int* src = ei;
    const int* dst = ei + N_EDGES;

    // workspace layout (16B-aligned regions)
    char* ws = (char*)d_ws;
    int* cursor   = (int*)ws;                                  // 512
    int* offsets  = cursor + 512;                              // N+16
    int* csr_src  = offsets + N_NODES + 16;                    // E+64
    unsigned char*  xq  = (unsigned char*)(csr_src + N_EDGES + 64);   // [2][N][64] i8
    unsigned short* xh  = (unsigned short*)(xq + (size_t)N_NODES * 128); // [N][128] bf16
    unsigned short* mh  = xh + (size_t)N_NODES * 128;                 // [N][128] bf16
    unsigned char*  zq  = (unsigned char*)(mh + (size_t)N_NODES * 128); // [N][64] i8
    unsigned short* pout = (unsigned short*)(zq + (size_t)N_NODES * 64); // [N][64] bf16
    unsigned short* WT1  = pout + (size_t)N_NODES * 64;               // 128*256 (swizzled)
    unsigned short* WT2T = WT1 + 128 * 256;                           // 128*128 (swizzled)
    unsigned* binned = (unsigned*)mh;   // alias mh: dead until agg1 writes it

    hipMemsetAsync(cursor, 0, NBKT * sizeof(int), stream);

    bin_kernel<<<(N_EDGES + BIN_CHUNK - 1) / BIN_CHUNK, 256, 0, stream>>>(
        src, dst, cursor, binned);

    // csr (391 blocks) overlapped with x-convert (25000) + W transpose (192)
    csr_conv_kernel<<<CC_CSR + CC_CONV + CC_WT, 256, 0, stream>>>(
        binned, cursor, offsets, csr_src, x, xh, xq,
        W1l, W1r, W2l, W2r, WT1, WT2T);

    // layer 1 aggregation, XCD-chunked x2
    const int a1b = ((N_NODES + 63) / 64) * 2;      // 3126
    agg1_int8<<<a1b, 256, 0, stream>>>(xq, offsets, csr_src, mh);

    // fused layer-1 + layer-2 GEMMs: 512 threads, 8 waves x 16 rows
    gemm12_kernel<<<(N_NODES + 127) / 128, 512, 0, stream>>>(
        mh, xh, WT1, WT2T, b1, b2, zq, pout);

    // layer-2 aggregation + final add
    agg2_out_kernel<<<N_NODES / 32, 256, 0, stream>>>(zq, pout, offsets, csr_src, out);
}